// Round 1
// baseline (1536.325 us; speedup 1.0000x reference)
//
#include <hip/hip_runtime.h>

#define D_ 128
#define C_ 4
#define B_ 2
#define F_ 256
#define T_ 256
#define NT 32           // tokens per block
#define STRIDE 132      // padded LDS row stride (floats), 16B-aligned rows, odd/4 banks
#define FT (F_*T_)

// ---------------------------------------------------------------------------
// Precompute effective (LN+proj+in_proj)-fused weights:
//   A    = in_w_block @ W          (128x128)
//   Ag   = A * g (LN gain, per input col)
//   sA_j = sum_i A[j][i]*g[i]
//   cb_j = sum_i A[j][i]*b_ln[i] + in_b[j] + sum_m in_w[j][m]*bW[m]
// Then proj_j(x) = r*(dot(Ag_j, x_raw) - m*sA_j) + cb_j
// ---------------------------------------------------------------------------
__global__ __launch_bounds__(128) void precompute_eff(
    const float* __restrict__ lnqg, const float* __restrict__ lnqb,
    const float* __restrict__ lnkg, const float* __restrict__ lnkb,
    const float* __restrict__ Wq, const float* __restrict__ bq,
    const float* __restrict__ Wk, const float* __restrict__ bk,
    const float* __restrict__ Wv, const float* __restrict__ bv,
    const float* __restrict__ in_w, const float* __restrict__ in_b,
    float* __restrict__ Ag, float* __restrict__ sA, float* __restrict__ cb)
{
    const int j = blockIdx.x;      // output row 0..127
    const int sel = blockIdx.y;    // 0=q, 1=k, 2=v
    const int i = threadIdx.x;     // input col 0..127
    const float* W  = (sel==0) ? Wq : (sel==1) ? Wk : Wv;
    const float* bW = (sel==0) ? bq : (sel==1) ? bk : bv;
    const float* g  = (sel==0) ? lnqg : lnkg;
    const float* bl = (sel==0) ? lnqb : lnkb;

    __shared__ float row[D_];
    __shared__ float red[D_];
    row[i] = in_w[(sel*D_ + j)*D_ + i];
    __syncthreads();
    float acc = 0.f;
    #pragma unroll 8
    for (int m = 0; m < D_; ++m) acc = fmaf(row[m], W[m*D_ + i], acc);
    float ag = acc * g[i];
    Ag[sel*D_*D_ + j*D_ + i] = ag;

    red[i] = ag;
    __syncthreads();
    for (int s = 64; s > 0; s >>= 1) { if (i < s) red[i] += red[i+s]; __syncthreads(); }
    if (i == 0) sA[sel*D_ + j] = red[0];
    __syncthreads();
    red[i] = acc * bl[i] + row[i] * bW[i];
    __syncthreads();
    for (int s = 64; s > 0; s >>= 1) { if (i < s) red[i] += red[i+s]; __syncthreads(); }
    if (i == 0) cb[sel*D_ + j] = red[0] + in_b[sel*D_ + j];
}

// ---------------------------------------------------------------------------
// Fused main kernel: per block = 32 tokens of one (b, f). Online-softmax over
// the C=4 contexts; q and ctx live in per-thread registers (thread = (t,h,half)).
// ---------------------------------------------------------------------------
__global__ __launch_bounds__(256, 3) void cca_main(
    const float* __restrict__ h,      // (C,B,D,F,T)
    const float* __restrict__ Ag,     // 3 x 128x128  (q,k,v)
    const float* __restrict__ sA,     // 3 x 128
    const float* __restrict__ cb,     // 3 x 128
    const float* __restrict__ out_w,  // 128x128
    const float* __restrict__ out_b,  // 128
    float* __restrict__ outp)         // (B,D,F,T)
{
    __shared__ float x0[NT*STRIDE];   // raw h_ref tile  [t][d]
    __shared__ float xc[NT*STRIDE];   // raw h_c tile    [t][d]
    __shared__ float kv[NT*STRIDE];   // q / k / v / ctx staging [t][j]
    __shared__ float mr[4*NT];        // m0, r0, mc, rc
    __shared__ float red[2*256];

    const int tid = threadIdx.x;
    const int blk = blockIdx.x;                  // 4096 = 2*256*8
    const int t0 = (blk & 7) * NT;
    const int f  = (blk >> 3) & 255;
    const int b  = blk >> 11;

    // GEMM tiling: 8 tokens x 2 outputs per thread
    const int jg = tid & 63;
    const int tg = tid >> 6;

    // attention mapping: thread = (token, head, half-of-32)
    const int at  = tid >> 3;
    const int ah  = (tid >> 1) & 3;
    const int ahalf = tid & 1;
    const int qoff = at*STRIDE + ah*32 + ahalf*16;

    // ---- tile loader: (c,b,:,f,t0..t0+31) -> dst[t][d], coalesced on t ----
    auto load_tile = [&](int c, float* dst) {
        const size_t base = ((size_t)(c*B_ + b) * D_) * FT + (size_t)f*T_ + t0;
        const int t4 = (tid & 7) * 4;
        const int dd = tid >> 3;
        #pragma unroll
        for (int it = 0; it < 4; ++it) {
            const int d = it*32 + dd;
            float4 v = *(const float4*)(h + base + (size_t)d*FT + t4);
            dst[(t4+0)*STRIDE + d] = v.x;
            dst[(t4+1)*STRIDE + d] = v.y;
            dst[(t4+2)*STRIDE + d] = v.z;
            dst[(t4+3)*STRIDE + d] = v.w;
        }
    };

    // ---- per-token mean / rstd over d (biased var, eps=1e-5) ----
    auto stats = [&](const float* X, float* m_out, float* r_out) {
        const int t = tid >> 3, g8 = tid & 7;
        float s = 0.f, sq = 0.f;
        #pragma unroll
        for (int i = 0; i < 16; ++i) {
            float v = X[t*STRIDE + g8 + 8*i];
            s += v; sq += v*v;
        }
        red[tid] = s; red[256 + tid] = sq;
        __syncthreads();
        if (tid < NT) {
            float ss = 0.f, qq = 0.f;
            #pragma unroll
            for (int u = 0; u < 8; ++u) { ss += red[tid*8+u]; qq += red[256 + tid*8+u]; }
            float m = ss * (1.f/128.f);
            float var = qq * (1.f/128.f) - m*m;
            m_out[tid] = m;
            r_out[tid] = rsqrtf(var + 1e-5f);
        }
        __syncthreads();
    };

    float acc[8][2];

    // ---- 32x128x128 GEMM: acc[tt][jj] = dot(X[t], A[j]) ----
    auto gemm = [&](const float* X, const float* __restrict__ A) {
        #pragma unroll
        for (int tt = 0; tt < 8; ++tt) { acc[tt][0] = 0.f; acc[tt][1] = 0.f; }
        const float* Xb = X + tg*8*STRIDE;
        #pragma unroll 4
        for (int k4 = 0; k4 < 32; ++k4) {
            float4 a0 = *(const float4*)(A + (size_t)jg*D_ + k4*4);
            float4 a1 = *(const float4*)(A + (size_t)(jg+64)*D_ + k4*4);
            #pragma unroll
            for (int tt = 0; tt < 8; ++tt) {
                float4 xv = *(const float4*)(Xb + tt*STRIDE + k4*4);
                acc[tt][0] = fmaf(xv.x,a0.x, fmaf(xv.y,a0.y, fmaf(xv.z,a0.z, fmaf(xv.w,a0.w, acc[tt][0]))));
                acc[tt][1] = fmaf(xv.x,a1.x, fmaf(xv.y,a1.y, fmaf(xv.z,a1.z, fmaf(xv.w,a1.w, acc[tt][1]))));
            }
        }
    };

    // ---- projection epilogue: LN-fold, write to kv[t][j] ----
    auto epi_proj = [&](const float* sAp, const float* cbp, const float* ms, const float* rs) {
        const float sa0 = sAp[jg], sa1 = sAp[jg+64];
        const float cb0 = cbp[jg], cb1 = cbp[jg+64];
        #pragma unroll
        for (int tt = 0; tt < 8; ++tt) {
            const int t = tg*8 + tt;
            const float m = ms[t], r = rs[t];
            kv[t*STRIDE + jg]      = fmaf(r, acc[tt][0] - m*sa0, cb0);
            kv[t*STRIDE + jg + 64] = fmaf(r, acc[tt][1] - m*sa1, cb1);
        }
    };

    // ================= phase 0: h_ref tile, stats, q =================
    load_tile(0, x0);
    __syncthreads();
    stats(x0, mr, mr + NT);
    gemm(x0, Ag);                       // q
    epi_proj(sA, cb, mr, mr + NT);
    __syncthreads();

    float qreg[16], ctx[16];
    #pragma unroll
    for (int i = 0; i < 16; ++i) { qreg[i] = kv[qoff + i]; ctx[i] = 0.f; }
    float mrun = -1e30f, lrun = 0.f;
    __syncthreads();                    // q reads done before k overwrites kv

    // ================= phase 1: online attention over c =================
    for (int c = 0; c < C_; ++c) {
        const float* X;
        const float *ms, *rs;
        if (c == 0) { X = x0; ms = mr; rs = mr + NT; }
        else {
            load_tile(c, xc);
            __syncthreads();
            stats(xc, mr + 2*NT, mr + 3*NT);
            X = xc; ms = mr + 2*NT; rs = mr + 3*NT;
        }
        gemm(X, Ag + D_*D_);            // k
        epi_proj(sA + D_, cb + D_, ms, rs);
        __syncthreads();

        float s = 0.f;
        #pragma unroll
        for (int i = 0; i < 16; ++i) s = fmaf(qreg[i], kv[qoff + i], s);
        s += __shfl_xor(s, 1);
        s *= 0.17677669529663687f;      // 1/sqrt(32)
        const float mn = fmaxf(mrun, s);
        const float al = __expf(mrun - mn);
        const float p  = __expf(s - mn);
        lrun = fmaf(lrun, al, p);
        mrun = mn;
        __syncthreads();                // score reads done before v overwrites kv

        gemm(X, Ag + 2*D_*D_);          // v
        epi_proj(sA + 2*D_, cb + 2*D_, ms, rs);
        __syncthreads();

        #pragma unroll
        for (int i = 0; i < 16; ++i) ctx[i] = fmaf(ctx[i], al, p * kv[qoff + i]);
        __syncthreads();                // ctx reads done before next k
    }

    // ================= phase 2: out-proj + residual =================
    const float inv = 1.f / lrun;
    #pragma unroll
    for (int i = 0; i < 16; ++i) kv[qoff + i] = ctx[i] * inv;
    __syncthreads();

    gemm(kv, out_w);
    {
        #pragma unroll
        for (int jj = 0; jj < 2; ++jj) {
            const int j = jg + 64*jj;
            const float ob = out_b[j];
            #pragma unroll
            for (int q4 = 0; q4 < 2; ++q4) {
                float4 o;
                o.x = acc[q4*4+0][jj] + ob + x0[(tg*8+q4*4+0)*STRIDE + j];
                o.y = acc[q4*4+1][jj] + ob + x0[(tg*8+q4*4+1)*STRIDE + j];
                o.z = acc[q4*4+2][jj] + ob + x0[(tg*8+q4*4+2)*STRIDE + j];
                o.w = acc[q4*4+3][jj] + ob + x0[(tg*8+q4*4+3)*STRIDE + j];
                *(float4*)(outp + ((size_t)(b*D_ + j))*FT + (size_t)f*T_ + t0 + tg*8 + q4*4) = o;
            }
        }
    }
}

extern "C" void kernel_launch(void* const* d_in, const int* in_sizes, int n_in,
                              void* d_out, int out_size, void* d_ws, size_t ws_size,
                              hipStream_t stream) {
    const float* h    = (const float*)d_in[0];
    const float* lnqg = (const float*)d_in[1];
    const float* lnqb = (const float*)d_in[2];
    const float* lnkg = (const float*)d_in[3];
    const float* lnkb = (const float*)d_in[4];
    const float* Wq   = (const float*)d_in[5];
    const float* bq   = (const float*)d_in[6];
    const float* Wk   = (const float*)d_in[7];
    const float* bk   = (const float*)d_in[8];
    const float* Wv   = (const float*)d_in[9];
    const float* bv   = (const float*)d_in[10];
    const float* in_w = (const float*)d_in[11];
    const float* in_b = (const float*)d_in[12];
    const float* ow   = (const float*)d_in[13];
    const float* ob   = (const float*)d_in[14];

    float* ws  = (float*)d_ws;
    float* Ag  = ws;                    // 3*16384
    float* sAe = ws + 3*D_*D_;          // 3*128
    float* cbe = ws + 3*D_*D_ + 3*D_;   // 3*128

    dim3 gp(128, 3);
    precompute_eff<<<gp, 128, 0, stream>>>(lnqg, lnqb, lnkg, lnkb,
                                           Wq, bq, Wk, bk, Wv, bv,
                                           in_w, in_b, Ag, sAe, cbe);
    cca_main<<<dim3(B_*F_*(T_/NT)), 256, 0, stream>>>(h, Ag, sAe, cbe, ow, ob, (float*)d_out);
}

// Round 2
// 479.110 us; speedup vs baseline: 3.2066x; 3.2066x over previous
//
#include <hip/hip_runtime.h>
#include <hip/hip_bf16.h>

typedef unsigned short u16;
typedef unsigned int   u32;

#define D_ 128
#define B_ 2
#define F_ 256
#define T_ 256
#define FT (F_*T_)
#define XS 136     // ushort stride of bf16 x tiles (16B-aligned rows)

typedef __bf16 bf16x8 __attribute__((ext_vector_type(8)));
typedef float  floatx16 __attribute__((ext_vector_type(16)));

__device__ __forceinline__ u16 f2bf(float f) {
    union { __hip_bfloat16 h; u16 u; } cv; cv.h = __float2bfloat16(f); return cv.u;
}
__device__ __forceinline__ u32 pk2(float lo, float hi2) {
    union { __hip_bfloat162 h; u32 u; } cv;
    cv.h = __float22bfloat162_rn(make_float2(lo, hi2)); return cv.u;
}
__device__ __forceinline__ float bf2f(u16 u) { return __uint_as_float(((u32)u) << 16); }

// ---------------------------------------------------------------------------
// Precompute effective fused weights (LN-gain + proj + in_proj composed):
//   A[j][i] = sum_m in_w[sel*D+j][m] * W[m][i]
//   Agb = bf16(A * g); sA_j = sum_i A[j][i]*g[i]
//   cb_j = sum_i A[j][i]*bl[i] + in_b[sel*D+j] + sum_m in_w[j][m]*bW[m]
// sel==3: just convert out_w to bf16.
// ---------------------------------------------------------------------------
__global__ __launch_bounds__(128) void precompute_eff(
    const float* __restrict__ lnqg, const float* __restrict__ lnqb,
    const float* __restrict__ lnkg, const float* __restrict__ lnkb,
    const float* __restrict__ Wq, const float* __restrict__ bq,
    const float* __restrict__ Wk, const float* __restrict__ bk,
    const float* __restrict__ Wv, const float* __restrict__ bv,
    const float* __restrict__ in_w, const float* __restrict__ in_b,
    const float* __restrict__ ow,
    u16* __restrict__ Agb, u16* __restrict__ Ob,
    float* __restrict__ sA, float* __restrict__ cb)
{
    const int j = blockIdx.x;      // output row 0..127
    const int sel = blockIdx.y;    // 0=q, 1=k, 2=v, 3=out_w convert
    const int i = threadIdx.x;     // input col 0..127
    if (sel == 3) { Ob[j*D_ + i] = f2bf(ow[j*D_ + i]); return; }

    const float* W  = (sel==0) ? Wq : (sel==1) ? Wk : Wv;
    const float* bW = (sel==0) ? bq : (sel==1) ? bk : bv;
    const float* g  = (sel==0) ? lnqg : lnkg;
    const float* bl = (sel==0) ? lnqb : lnkb;

    __shared__ float row[D_];
    __shared__ float red[D_];
    row[i] = in_w[(sel*D_ + j)*D_ + i];
    __syncthreads();
    float acc = 0.f;
    #pragma unroll 8
    for (int m = 0; m < D_; ++m) acc = fmaf(row[m], W[m*D_ + i], acc);
    float ag = acc * g[i];
    Agb[sel*D_*D_ + j*D_ + i] = f2bf(ag);

    red[i] = ag;
    __syncthreads();
    for (int s = 64; s > 0; s >>= 1) { if (i < s) red[i] += red[i+s]; __syncthreads(); }
    if (i == 0) sA[sel*D_ + j] = red[0];
    __syncthreads();
    red[i] = acc * bl[i] + row[i] * bW[i];
    __syncthreads();
    for (int s = 64; s > 0; s >>= 1) { if (i < s) red[i] += red[i+s]; __syncthreads(); }
    if (i == 0) cb[sel*D_ + j] = red[0] + in_b[sel*D_ + j];
}

// ---------------------------------------------------------------------------
// Main fused kernel. Block = 32 tokens of one (b,f). 4 waves, wave = head.
// MFMA 32x32x16 bf16; q/ctx live in C-frag registers; 3 barriers total.
// ---------------------------------------------------------------------------
__global__ __launch_bounds__(256, 3) void cca_mfma(
    const float* __restrict__ h,      // (C,B,128,F,T) fp32
    const u16*  __restrict__ Agb,     // 3 x [128][128] bf16 (q,k,v fused)
    const u16*  __restrict__ Ob,      // [128][128] bf16 out_w
    const float* __restrict__ sA,     // 3x128
    const float* __restrict__ cbp,    // 3x128
    const float* __restrict__ out_b,  // 128
    float* __restrict__ outp)         // (B,128,F,T)
{
    __shared__ __align__(16) u16 xb[4][32*XS];   // raw x tiles, bf16 [t][d]
    __shared__ __align__(16) u16 ctxb[32*XS];    // normalized ctx, bf16 [t][j]
    __shared__ float  swt[4][4][32];             // [head][c][t] scores -> weights
    __shared__ float2 stf[4][32];                // [c][t] = (mean, rstd)

    const int tid = threadIdx.x;
    const int blk = blockIdx.x;                  // 4096 = 2*256*8
    const int t0 = (blk & 7) * 32;
    const int f  = (blk >> 3) & 255;
    const int b  = blk >> 11;

    // ---------------- load all 4 context tiles (fp32 -> bf16 packed) -------
    {
        const int dd = tid >> 3;          // d-pair index 0..31
        const int t4 = (tid & 7) * 4;
        #pragma unroll
        for (int it = 0; it < 2; ++it) {
            const int d = 2*dd + 64*it;
            #pragma unroll
            for (int c = 0; c < 4; ++c) {
                const float* p = h + ((size_t)((c*B_ + b)*D_ + d))*FT + (size_t)f*T_ + t0 + t4;
                float4 v0 = *(const float4*)p;
                float4 v1 = *(const float4*)(p + FT);
                u32* dst = (u32*)xb[c] + dd + 32*it;     // dword (d,d+1) column
                dst[(size_t)(t4+0)*(XS/2)] = pk2(v0.x, v1.x);
                dst[(size_t)(t4+1)*(XS/2)] = pk2(v0.y, v1.y);
                dst[(size_t)(t4+2)*(XS/2)] = pk2(v0.z, v1.z);
                dst[(size_t)(t4+3)*(XS/2)] = pk2(v0.w, v1.w);
            }
        }
    }
    __syncthreads();

    // ---------------- per-(c,token) mean / rstd from bf16 tiles ------------
    if (tid < 128) {
        const int c = tid >> 5, t = tid & 31;
        const u32* row = (const u32*)(xb[c] + t*XS);
        float s = 0.f, sq = 0.f;
        #pragma unroll
        for (int i = 0; i < 16; ++i) {
            uint4 w = *(const uint4*)(row + i*4);
            const u32 us[4] = {w.x, w.y, w.z, w.w};
            #pragma unroll
            for (int k = 0; k < 4; ++k) {
                float lo = __uint_as_float(us[k] << 16);
                float hi = __uint_as_float(us[k] & 0xffff0000u);
                s += lo + hi;
                sq = fmaf(lo, lo, fmaf(hi, hi, sq));
            }
        }
        float m = s * (1.f/128.f);
        float var = fmaf(-m, m, sq * (1.f/128.f));
        stf[c][t] = make_float2(m, rsqrtf(var + 1e-5f));
    }
    __syncthreads();

    // ---------------- per-wave setup (wave = head) -------------------------
    const int wv  = tid >> 6;          // head 0..3 == n-tile
    const int l   = tid & 63;
    const int lo5 = l & 31, hi = l >> 5;
    const int jq  = wv*32 + lo5;       // this lane's output column
    const int xoff = lo5*XS + hi*8;    // A-frag base (ushort units), + ks*16

    const u16* Bq = Agb +            (size_t)jq*D_ + hi*8;
    const u16* Bk = Agb + 16384 +    (size_t)jq*D_ + hi*8;
    const u16* Bv = Agb + 32768 +    (size_t)jq*D_ + hi*8;
    const u16* Bo = Ob  +            (size_t)jq*D_ + hi*8;
    const float sAq = sA[jq],      cbq = cbp[jq];
    const float sAk = sA[128+jq],  cbk = cbp[128+jq];
    const float sAv = sA[256+jq],  cbv = cbp[256+jq];

    auto gemm32 = [&](const u16* X, const u16* Bp) {
        floatx16 acc;
        #pragma unroll
        for (int i = 0; i < 16; ++i) acc[i] = 0.f;
        #pragma unroll
        for (int ks = 0; ks < 8; ++ks) {
            bf16x8 a  = *(const bf16x8*)(X + xoff + ks*16);
            bf16x8 bb = *(const bf16x8*)(Bp + ks*16);
            acc = __builtin_amdgcn_mfma_f32_32x32x16_bf16(a, bb, acc, 0, 0, 0);
        }
        return acc;
    };
    // LN fold: y = r*(acc - m*sAx) + cbx   (t per reg: (i&3)+8*(i>>2)+4*hi)
    auto fold = [&](floatx16& acc, int c, float sAx, float cbx) {
        #pragma unroll
        for (int i = 0; i < 16; ++i) {
            const int t = (i&3) + 8*(i>>2) + 4*hi;
            float2 mr = stf[c][t];
            acc[i] = fmaf(mr.y, fmaf(-mr.x, sAx, acc[i]), cbx);
        }
    };

    // ---------------- q (this head's 32 columns, in registers) -------------
    floatx16 qv = gemm32(xb[0], Bq);
    fold(qv, 0, sAq, cbq);

    // ---------------- k phase: scores via in-register butterfly ------------
    #pragma unroll
    for (int c = 0; c < 4; ++c) {
        floatx16 kv = gemm32(xb[c], Bk);
        fold(kv, c, sAk, cbk);
        floatx16 p;
        #pragma unroll
        for (int i = 0; i < 16; ++i) p[i] = qv[i] * kv[i];
        #pragma unroll
        for (int msk = 1; msk <= 16; msk <<= 1) {
            #pragma unroll
            for (int i = 0; i < 16; ++i) p[i] += __shfl_xor(p[i], msk);
        }
        if (lo5 == 0) {
            #pragma unroll
            for (int i = 0; i < 16; ++i)
                swt[wv][c][(i&3) + 8*(i>>2) + 4*hi] = p[i] * 0.17677669529663687f;
        }
    }

    // ---------------- softmax over c (per wave, no barrier) ----------------
    #pragma unroll
    for (int i = 0; i < 16; ++i) {
        const int t = (i&3) + 8*(i>>2) + 4*hi;
        float s0 = swt[wv][0][t], s1 = swt[wv][1][t];
        float s2 = swt[wv][2][t], s3 = swt[wv][3][t];
        float mm = fmaxf(fmaxf(s0, s1), fmaxf(s2, s3));
        float e0 = __expf(s0-mm), e1 = __expf(s1-mm);
        float e2 = __expf(s2-mm), e3 = __expf(s3-mm);
        float inv = 1.f / (e0+e1+e2+e3);
        if (lo5 == 0) {
            swt[wv][0][t] = e0*inv; swt[wv][1][t] = e1*inv;
            swt[wv][2][t] = e2*inv; swt[wv][3][t] = e3*inv;
        }
    }

    // ---------------- v phase: weighted accumulate in registers ------------
    floatx16 ctx;
    #pragma unroll
    for (int i = 0; i < 16; ++i) ctx[i] = 0.f;
    #pragma unroll
    for (int c = 0; c < 4; ++c) {
        floatx16 vv = gemm32(xb[c], Bv);
        fold(vv, c, sAv, cbv);
        #pragma unroll
        for (int i = 0; i < 16; ++i) {
            const int t = (i&3) + 8*(i>>2) + 4*hi;
            ctx[i] = fmaf(swt[wv][c][t], vv[i], ctx[i]);
        }
    }

    // ---------------- ctx -> LDS (bf16), out-proj, residual, store ---------
    #pragma unroll
    for (int i = 0; i < 16; ++i) {
        const int t = (i&3) + 8*(i>>2) + 4*hi;
        ctxb[t*XS + jq] = f2bf(ctx[i]);
    }
    __syncthreads();

    floatx16 o = gemm32(ctxb, Bo);
    const float obv = out_b[jq];
    float* obase = outp + ((size_t)(b*D_ + jq))*FT + (size_t)f*T_ + t0;
    #pragma unroll
    for (int g = 0; g < 4; ++g) {
        const int tb = 8*g + 4*hi;
        float4 st;
        st.x = o[g*4+0] + obv + bf2f(xb[0][(tb+0)*XS + jq]);
        st.y = o[g*4+1] + obv + bf2f(xb[0][(tb+1)*XS + jq]);
        st.z = o[g*4+2] + obv + bf2f(xb[0][(tb+2)*XS + jq]);
        st.w = o[g*4+3] + obv + bf2f(xb[0][(tb+3)*XS + jq]);
        *(float4*)(obase + tb) = st;
    }
}

extern "C" void kernel_launch(void* const* d_in, const int* in_sizes, int n_in,
                              void* d_out, int out_size, void* d_ws, size_t ws_size,
                              hipStream_t stream) {
    const float* h    = (const float*)d_in[0];
    const float* lnqg = (const float*)d_in[1];
    const float* lnqb = (const float*)d_in[2];
    const float* lnkg = (const float*)d_in[3];
    const float* lnkb = (const float*)d_in[4];
    const float* Wq   = (const float*)d_in[5];
    const float* bq   = (const float*)d_in[6];
    const float* Wk   = (const float*)d_in[7];
    const float* bk   = (const float*)d_in[8];
    const float* Wv   = (const float*)d_in[9];
    const float* bv   = (const float*)d_in[10];
    const float* in_w = (const float*)d_in[11];
    const float* in_b = (const float*)d_in[12];
    const float* ow   = (const float*)d_in[13];
    const float* ob   = (const float*)d_in[14];

    char* ws = (char*)d_ws;
    u16*   Agb = (u16*)ws;                          // 3*16384 u16 = 98304 B
    u16*   Obf = (u16*)(ws + 98304);                // 16384 u16  = 32768 B
    float* sAe = (float*)(ws + 98304 + 32768);      // 384 f
    float* cbe = (float*)(ws + 98304 + 32768 + 1536);

    precompute_eff<<<dim3(128, 4), 128, 0, stream>>>(
        lnqg, lnqb, lnkg, lnkb, Wq, bq, Wk, bk, Wv, bv,
        in_w, in_b, ow, Agb, Obf, sAe, cbe);
    cca_mfma<<<dim3(B_*F_*(T_/32)), 256, 0, stream>>>(
        h, Agb, Obf, sAe, cbe, ob, (float*)d_out);
}

// Round 3
// 467.742 us; speedup vs baseline: 3.2846x; 1.0243x over previous
//
#include <hip/hip_runtime.h>
#include <hip/hip_bf16.h>

typedef unsigned short u16;
typedef unsigned int   u32;

#define D_ 128
#define B_ 2
#define F_ 256
#define T_ 256
#define FT (F_*T_)
#define XS 136     // ushort stride of x tiles
#define QS 40      // ushort stride of per-wave q/k stage (32 cols + pad)

typedef __bf16 bf16x8 __attribute__((ext_vector_type(8)));
typedef float  floatx16 __attribute__((ext_vector_type(16)));

#define LGKM0 asm volatile("s_waitcnt lgkmcnt(0)" ::: "memory")

__device__ __forceinline__ u16 f2bf(float f) {
    union { __hip_bfloat16 h; u16 u; } cv; cv.h = __float2bfloat16(f); return cv.u;
}
__device__ __forceinline__ u32 pk2(float lo, float hi2) {
    union { __hip_bfloat162 h; u32 u; } cv;
    cv.h = __float22bfloat162_rn(make_float2(lo, hi2)); return cv.u;
}
__device__ __forceinline__ float bf2f(u16 u) { return __uint_as_float(((u32)u) << 16); }

// ---------------------------------------------------------------------------
// Precompute effective fused weights (identical math to round 2).
// ---------------------------------------------------------------------------
__global__ __launch_bounds__(128) void precompute_eff(
    const float* __restrict__ lnqg, const float* __restrict__ lnqb,
    const float* __restrict__ lnkg, const float* __restrict__ lnkb,
    const float* __restrict__ Wq, const float* __restrict__ bq,
    const float* __restrict__ Wk, const float* __restrict__ bk,
    const float* __restrict__ Wv, const float* __restrict__ bv,
    const float* __restrict__ in_w, const float* __restrict__ in_b,
    const float* __restrict__ ow,
    u16* __restrict__ Agb, u16* __restrict__ Ob,
    float* __restrict__ sA, float* __restrict__ cb)
{
    const int j = blockIdx.x;
    const int sel = blockIdx.y;    // 0=q,1=k,2=v,3=out_w convert
    const int i = threadIdx.x;
    if (sel == 3) { Ob[j*D_ + i] = f2bf(ow[j*D_ + i]); return; }

    const float* W  = (sel==0) ? Wq : (sel==1) ? Wk : Wv;
    const float* bW = (sel==0) ? bq : (sel==1) ? bk : bv;
    const float* g  = (sel==0) ? lnqg : lnkg;
    const float* bl = (sel==0) ? lnqb : lnkb;

    __shared__ float row[D_];
    __shared__ float red[D_];
    row[i] = in_w[(sel*D_ + j)*D_ + i];
    __syncthreads();
    float acc = 0.f;
    #pragma unroll 8
    for (int m = 0; m < D_; ++m) acc = fmaf(row[m], W[m*D_ + i], acc);
    float ag = acc * g[i];
    Agb[sel*D_*D_ + j*D_ + i] = f2bf(ag);

    red[i] = ag;
    __syncthreads();
    for (int s = 64; s > 0; s >>= 1) { if (i < s) red[i] += red[i+s]; __syncthreads(); }
    if (i == 0) sA[sel*D_ + j] = red[0];
    __syncthreads();
    red[i] = acc * bl[i] + row[i] * bW[i];
    __syncthreads();
    for (int s = 64; s > 0; s >>= 1) { if (i < s) red[i] += red[i+s]; __syncthreads(); }
    if (i == 0) cb[sel*D_ + j] = red[0] + in_b[sel*D_ + j];
}

// ---------------------------------------------------------------------------
// Main fused kernel. Block = 32 tokens of one (b,f). 4 waves, wave = head.
// x tiles stored r-scaled in LDS; scores via per-wave Q·K^T MFMA + diag pick.
// ---------------------------------------------------------------------------
__global__ __launch_bounds__(256, 3) void cca_mfma(
    const float* __restrict__ h,      // (C,B,128,F,T) fp32
    const u16*  __restrict__ Agb,     // 3 x [128][128] bf16 (q,k,v fused)
    const u16*  __restrict__ Ob,      // [128][128] bf16 out_w
    const float* __restrict__ sA,     // 3x128
    const float* __restrict__ cbp,    // 3x128
    const float* __restrict__ out_b,  // 128
    float* __restrict__ outp)         // (B,128,F,T)
{
    __shared__ __align__(16) u16 xb[4][32*XS];    // 34816 B, r-scaled bf16 x
    __shared__ __align__(16) u16 qk[4][32*QS];    // 10240 B, per-wave q/k stage
    __shared__ float swt[4][4][32];               // 2048 B  [head][c][t] weights
    __shared__ float rmneg[4][32];                // 512 B   -r*m per (c,t)
    __shared__ float invr[32];                    // 128 B   1/r for c=0

    const int tid = threadIdx.x;
    const int blk = blockIdx.x;                  // 4096 = 2*256*8
    const int t0 = (blk & 7) * 32;
    const int f  = (blk >> 3) & 255;
    const int b  = blk >> 11;

    // ---------------- load all 4 context tiles (fp32 -> bf16 packed) -------
    {
        const int dd = tid >> 3;          // d-pair index 0..31
        const int t4 = (tid & 7) * 4;
        #pragma unroll
        for (int it = 0; it < 2; ++it) {
            const int d = 2*dd + 64*it;
            #pragma unroll
            for (int c = 0; c < 4; ++c) {
                const float* p = h + ((size_t)((c*B_ + b)*D_ + d))*FT + (size_t)f*T_ + t0 + t4;
                float4 v0 = *(const float4*)p;
                float4 v1 = *(const float4*)(p + FT);
                u32* dst = (u32*)xb[c] + dd + 32*it;
                dst[(size_t)(t4+0)*(XS/2)] = pk2(v0.x, v1.x);
                dst[(size_t)(t4+1)*(XS/2)] = pk2(v0.y, v1.y);
                dst[(size_t)(t4+2)*(XS/2)] = pk2(v0.z, v1.z);
                dst[(size_t)(t4+3)*(XS/2)] = pk2(v0.w, v1.w);
            }
        }
    }
    __syncthreads();

    // ---------- stats + in-place r-scale (thread = half-row of (c,t)) ------
    {
        const int rowi = tid >> 1, half = tid & 1;
        const int c = rowi >> 5, t = rowi & 31;
        u32* rowp = (u32*)(xb[c] + t*XS) + half*32;
        u32 rw[32];
        #pragma unroll
        for (int i = 0; i < 8; ++i) {
            uint4 q = ((const uint4*)rowp)[i];
            rw[4*i] = q.x; rw[4*i+1] = q.y; rw[4*i+2] = q.z; rw[4*i+3] = q.w;
        }
        float s = 0.f, sq = 0.f;
        #pragma unroll
        for (int k = 0; k < 32; ++k) {
            float lo = __uint_as_float(rw[k] << 16);
            float hi2 = __uint_as_float(rw[k] & 0xffff0000u);
            s += lo + hi2;
            sq = fmaf(lo, lo, fmaf(hi2, hi2, sq));
        }
        s += __shfl_xor(s, 1);
        sq += __shfl_xor(sq, 1);
        float m = s * (1.f/128.f);
        float var = fmaf(-m, m, sq * (1.f/128.f));
        float r = rsqrtf(var + 1e-5f);
        #pragma unroll
        for (int i = 0; i < 8; ++i) {
            uint4 q;
            q.x = pk2(__uint_as_float(rw[4*i]   << 16)*r, __uint_as_float(rw[4*i]   & 0xffff0000u)*r);
            q.y = pk2(__uint_as_float(rw[4*i+1] << 16)*r, __uint_as_float(rw[4*i+1] & 0xffff0000u)*r);
            q.z = pk2(__uint_as_float(rw[4*i+2] << 16)*r, __uint_as_float(rw[4*i+2] & 0xffff0000u)*r);
            q.w = pk2(__uint_as_float(rw[4*i+3] << 16)*r, __uint_as_float(rw[4*i+3] & 0xffff0000u)*r);
            ((uint4*)rowp)[i] = q;
        }
        if (half == 0) {
            rmneg[c][t] = -r*m;
            if (c == 0) invr[t] = 1.0f / r;
        }
    }
    __syncthreads();

    // ---------------- per-wave setup (wave = head) -------------------------
    const int wv  = tid >> 6;
    const int l   = tid & 63;
    const int lo5 = l & 31, hi = l >> 5;
    const int jq  = wv*32 + lo5;
    u16* qkw = qk[wv];
    const int xoff  = lo5*XS + hi*8;
    const int qkoff = lo5*QS + hi*8;

    const u16* Bq = Agb +         (size_t)jq*D_ + hi*8;
    const u16* Bk = Agb + 16384 + (size_t)jq*D_ + hi*8;
    const u16* Bv = Agb + 32768 + (size_t)jq*D_ + hi*8;
    const u16* Bo = Ob  +         (size_t)jq*D_ + hi*8;
    const float sAq = sA[jq],      cbq = cbp[jq];
    const float sAk = sA[128+jq],  cbk = cbp[128+jq];
    const float sAv = sA[256+jq],  cbv = cbp[256+jq];

    // fold: acc[i] += fma(rmneg[c][t], sAx, cbx)
    auto foldv = [&](floatx16& a, int c, float sAx, float cbx) {
        #pragma unroll
        for (int g = 0; g < 4; ++g) {
            float4 rm4 = *(const float4*)&rmneg[c][8*g + 4*hi];
            a[4*g+0] += fmaf(rm4.x, sAx, cbx);
            a[4*g+1] += fmaf(rm4.y, sAx, cbx);
            a[4*g+2] += fmaf(rm4.z, sAx, cbx);
            a[4*g+3] += fmaf(rm4.w, sAx, cbx);
        }
    };
    // stage C-frag (this head's 32 cols) to qk buffer as [t][lo5]
    auto stage = [&](const floatx16& a) {
        #pragma unroll
        for (int i = 0; i < 16; ++i) {
            const int t = (i&3) + 8*(i>>2) + 4*hi;
            qkw[t*QS + lo5] = f2bf(a[i]);
        }
    };
    // diagonal pick: element with row==lo5 (valid when hi==(lo5>>2)&1)
    auto diag = [&](const floatx16& s2) -> float {
        const bool b0 = lo5 & 1, b1 = lo5 & 2, b2 = lo5 & 8, b3 = lo5 & 16;
        float t01 = b0 ? s2[1] : s2[0],  t23 = b0 ? s2[3] : s2[2];
        float t45 = b0 ? s2[5] : s2[4],  t67 = b0 ? s2[7] : s2[6];
        float t89 = b0 ? s2[9] : s2[8],  tab = b0 ? s2[11] : s2[10];
        float tcd = b0 ? s2[13] : s2[12], tef = b0 ? s2[15] : s2[14];
        float u0 = b1 ? t23 : t01, u1 = b1 ? t67 : t45;
        float u2 = b1 ? tab : t89, u3 = b1 ? tef : tcd;
        float v0 = b2 ? u1 : u0,  v1 = b2 ? u3 : u2;
        return b3 ? v1 : v0;
    };

    // ---------------- q: gemm + stage + A-frag readback --------------------
    floatx16 qa;
    #pragma unroll
    for (int i = 0; i < 16; ++i) qa[i] = 0.f;
    #pragma unroll
    for (int ks = 0; ks < 8; ++ks) {
        bf16x8 a  = *(const bf16x8*)(xb[0] + xoff + ks*16);
        bf16x8 bb = *(const bf16x8*)(Bq + ks*16);
        qa = __builtin_amdgcn_mfma_f32_32x32x16_bf16(a, bb, qa, 0, 0, 0);
    }
    foldv(qa, 0, sAq, cbq);
    stage(qa);
    LGKM0;
    bf16x8 qf0 = *(const bf16x8*)(qkw + qkoff);
    bf16x8 qf1 = *(const bf16x8*)(qkw + qkoff + 16);
    LGKM0;

    // ---------------- k phase: 4 accumulators (Bk reuse), scores -----------
    floatx16 ka0, ka1, ka2, ka3;
    #pragma unroll
    for (int i = 0; i < 16; ++i) { ka0[i]=0.f; ka1[i]=0.f; ka2[i]=0.f; ka3[i]=0.f; }
    #pragma unroll
    for (int ks = 0; ks < 8; ++ks) {
        bf16x8 bb = *(const bf16x8*)(Bk + ks*16);
        bf16x8 a0 = *(const bf16x8*)(xb[0] + xoff + ks*16);
        bf16x8 a1 = *(const bf16x8*)(xb[1] + xoff + ks*16);
        bf16x8 a2 = *(const bf16x8*)(xb[2] + xoff + ks*16);
        bf16x8 a3 = *(const bf16x8*)(xb[3] + xoff + ks*16);
        ka0 = __builtin_amdgcn_mfma_f32_32x32x16_bf16(a0, bb, ka0, 0, 0, 0);
        ka1 = __builtin_amdgcn_mfma_f32_32x32x16_bf16(a1, bb, ka1, 0, 0, 0);
        ka2 = __builtin_amdgcn_mfma_f32_32x32x16_bf16(a2, bb, ka2, 0, 0, 0);
        ka3 = __builtin_amdgcn_mfma_f32_32x32x16_bf16(a3, bb, ka3, 0, 0, 0);
    }
    float sreg[4];
    #pragma unroll
    for (int c = 0; c < 4; ++c) {
        floatx16& ka = (c==0) ? ka0 : (c==1) ? ka1 : (c==2) ? ka2 : ka3;
        foldv(ka, c, sAk, cbk);
        stage(ka);
        LGKM0;
        bf16x8 kf0 = *(const bf16x8*)(qkw + qkoff);
        bf16x8 kf1 = *(const bf16x8*)(qkw + qkoff + 16);
        LGKM0;
        floatx16 sc;
        #pragma unroll
        for (int i = 0; i < 16; ++i) sc[i] = 0.f;
        sc = __builtin_amdgcn_mfma_f32_32x32x16_bf16(qf0, kf0, sc, 0, 0, 0);
        sc = __builtin_amdgcn_mfma_f32_32x32x16_bf16(qf1, kf1, sc, 0, 0, 0);
        sreg[c] = diag(sc) * 0.17677669529663687f;   // 1/sqrt(32)
    }

    // ---------------- softmax (diag-owner lanes), broadcast via LDS --------
    {
        const bool active = (hi == ((lo5 >> 2) & 1));
        if (active) {
            float mm = fmaxf(fmaxf(sreg[0], sreg[1]), fmaxf(sreg[2], sreg[3]));
            float e0 = __expf(sreg[0]-mm), e1 = __expf(sreg[1]-mm);
            float e2 = __expf(sreg[2]-mm), e3 = __expf(sreg[3]-mm);
            float inv = 1.f / (e0+e1+e2+e3);
            swt[wv][0][lo5] = e0*inv; swt[wv][1][lo5] = e1*inv;
            swt[wv][2][lo5] = e2*inv; swt[wv][3][lo5] = e3*inv;
        }
    }
    LGKM0;

    // ---------------- v phase: 2 accs per pass, weighted into ctx ----------
    floatx16 ctx;
    #pragma unroll
    for (int i = 0; i < 16; ++i) ctx[i] = 0.f;
    #pragma unroll
    for (int cp = 0; cp < 4; cp += 2) {
        floatx16 va0, va1;
        #pragma unroll
        for (int i = 0; i < 16; ++i) { va0[i]=0.f; va1[i]=0.f; }
        #pragma unroll
        for (int ks = 0; ks < 8; ++ks) {
            bf16x8 bb = *(const bf16x8*)(Bv + ks*16);
            bf16x8 a0 = *(const bf16x8*)(xb[cp]   + xoff + ks*16);
            bf16x8 a1 = *(const bf16x8*)(xb[cp+1] + xoff + ks*16);
            va0 = __builtin_amdgcn_mfma_f32_32x32x16_bf16(a0, bb, va0, 0, 0, 0);
            va1 = __builtin_amdgcn_mfma_f32_32x32x16_bf16(a1, bb, va1, 0, 0, 0);
        }
        #pragma unroll
        for (int d = 0; d < 2; ++d) {
            const int c = cp + d;
            floatx16& va = d ? va1 : va0;
            foldv(va, c, sAv, cbv);
            #pragma unroll
            for (int g = 0; g < 4; ++g) {
                float4 w4 = *(const float4*)&swt[wv][c][8*g + 4*hi];
                ctx[4*g+0] = fmaf(w4.x, va[4*g+0], ctx[4*g+0]);
                ctx[4*g+1] = fmaf(w4.y, va[4*g+1], ctx[4*g+1]);
                ctx[4*g+2] = fmaf(w4.z, va[4*g+2], ctx[4*g+2]);
                ctx[4*g+3] = fmaf(w4.w, va[4*g+3], ctx[4*g+3]);
            }
        }
    }

    // ---------------- ctx -> xb[1] (bf16), out-proj, residual, store -------
    __syncthreads();                       // all waves done reading x tiles
    #pragma unroll
    for (int i = 0; i < 16; ++i) {
        const int t = (i&3) + 8*(i>>2) + 4*hi;
        xb[1][t*XS + jq] = f2bf(ctx[i]);
    }
    __syncthreads();                       // ctx visible to all waves

    floatx16 oa;
    #pragma unroll
    for (int i = 0; i < 16; ++i) oa[i] = 0.f;
    #pragma unroll
    for (int ks = 0; ks < 8; ++ks) {
        bf16x8 a  = *(const bf16x8*)(xb[1] + xoff + ks*16);
        bf16x8 bb = *(const bf16x8*)(Bo + ks*16);
        oa = __builtin_amdgcn_mfma_f32_32x32x16_bf16(a, bb, oa, 0, 0, 0);
    }
    const float obv = out_b[jq];
    float* obase = outp + ((size_t)(b*D_ + jq))*FT + (size_t)f*T_ + t0;
    #pragma unroll
    for (int g = 0; g < 4; ++g) {
        const int tb = 8*g + 4*hi;
        float4 iv4 = *(const float4*)&invr[tb];
        float4 st;
        st.x = oa[g*4+0] + obv + bf2f(xb[0][(tb+0)*XS + jq]) * iv4.x;
        st.y = oa[g*4+1] + obv + bf2f(xb[0][(tb+1)*XS + jq]) * iv4.y;
        st.z = oa[g*4+2] + obv + bf2f(xb[0][(tb+2)*XS + jq]) * iv4.z;
        st.w = oa[g*4+3] + obv + bf2f(xb[0][(tb+3)*XS + jq]) * iv4.w;
        *(float4*)(obase + tb) = st;
    }
}

extern "C" void kernel_launch(void* const* d_in, const int* in_sizes, int n_in,
                              void* d_out, int out_size, void* d_ws, size_t ws_size,
                              hipStream_t stream) {
    const float* h    = (const float*)d_in[0];
    const float* lnqg = (const float*)d_in[1];
    const float* lnqb = (const float*)d_in[2];
    const float* lnkg = (const float*)d_in[3];
    const float* lnkb = (const float*)d_in[4];
    const float* Wq   = (const float*)d_in[5];
    const float* bq   = (const float*)d_in[6];
    const float* Wk   = (const float*)d_in[7];
    const float* bk   = (const float*)d_in[8];
    const float* Wv   = (const float*)d_in[9];
    const float* bv   = (const float*)d_in[10];
    const float* in_w = (const float*)d_in[11];
    const float* in_b = (const float*)d_in[12];
    const float* ow   = (const float*)d_in[13];
    const float* ob   = (const float*)d_in[14];

    char* ws = (char*)d_ws;
    u16*   Agb = (u16*)ws;                          // 3*16384 u16 = 98304 B
    u16*   Obf = (u16*)(ws + 98304);                // 16384 u16  = 32768 B
    float* sAe = (float*)(ws + 98304 + 32768);      // 384 f
    float* cbe = (float*)(ws + 98304 + 32768 + 1536);

    precompute_eff<<<dim3(128, 4), 128, 0, stream>>>(
        lnqg, lnqb, lnkg, lnkb, Wq, bq, Wk, bk, Wv, bv,
        in_w, in_b, ow, Agb, Obf, sAe, cbe);
    cca_mfma<<<dim3(B_*F_*(T_/32)), 256, 0, stream>>>(
        h, Agb, Obf, sAe, cbe, ob, (float*)d_out);
}